// Round 1
// baseline (627.511 us; speedup 1.0000x reference)
//
#include <hip/hip_runtime.h>

#define NV 320
#define NB 32
#define NL 2048
#define ND 1024
#define CH 32            // l-chunks per batch
#define CL (NL / CH)     // 64 positions per chunk

typedef float f32x4 __attribute__((ext_vector_type(4)));

// Kernel A: per-batch histogram -> per-position prob -> per-batch sum.
// One block per batch, 256 threads. (unchanged from verified version)
__global__ __launch_bounds__(256) void vq_weights_kernel(
    const int* __restrict__ vq_indices,   // (B, L, 2) int32
    const int* __restrict__ lengths,      // (B,) int32
    float* __restrict__ prob,             // (B, L) ws
    float* __restrict__ sums)             // (B,)  ws
{
    __shared__ int cx[NV];
    __shared__ int cy[NV];
    __shared__ float wave_sums[4];

    const int b = blockIdx.x;
    const int t = threadIdx.x;

    for (int i = t; i < NV; i += 256) { cx[i] = 0; cy[i] = 0; }
    __syncthreads();

    const int2* idx = (const int2*)(vq_indices) + (size_t)b * NL;
    // histogram over ALL L positions (reference counts unmasked)
    for (int l = t; l < NL; l += 256) {
        int2 v = idx[l];
        atomicAdd(&cx[v.x], 1);
        atomicAdd(&cy[v.y], 1);
    }
    __syncthreads();

    const int len = lengths[b];
    float local = 0.f;
    for (int l = t; l < NL; l += 256) {
        int2 v = idx[l];
        float p = 0.f;
        if (l < len) p = 1.0f / (float)(cx[v.x] + cy[v.y]);
        prob[(size_t)b * NL + l] = p;
        local += p;
    }
    // wave64 reduce, then cross-wave via LDS
    for (int off = 32; off > 0; off >>= 1)
        local += __shfl_down(local, off, 64);
    if ((t & 63) == 0) wave_sums[t >> 6] = local;
    __syncthreads();
    if (t == 0)
        sums[b] = wave_sums[0] + wave_sums[1] + wave_sums[2] + wave_sums[3];
}

// Kernel B: partial[b][c][d] = sum_{l in chunk c} prob[b,l] * feat[b,1,l,d]
// grid = (CH, B), block = 256 threads, thread t owns float4 at d = 4t.
// NO atomics: each block owns its private partial slot.
__global__ __launch_bounds__(256) void vq_pool_kernel(
    const float* __restrict__ feature,    // (B, 2, L, D) f32
    const int* __restrict__ lengths,
    const float* __restrict__ prob,
    float* __restrict__ partial)          // (B, CH, D) ws
{
    const int c = blockIdx.x;
    const int b = blockIdx.y;
    const int len = lengths[b];
    const int l0 = c * CL;
    if (l0 >= len) return;                // fully masked chunk: reducer skips it
    const int l1 = min(l0 + CL, len);

    const int t = threadIdx.x;

    __shared__ float wloc[CL];
    if (t < CL) wloc[t] = prob[(size_t)b * NL + l0 + t];
    __syncthreads();

    // feat slice [b, n=1]: base offset (b*2 + 1) * L * D
    const f32x4* f4 = (const f32x4*)(feature + ((size_t)b * 2 + 1) * (size_t)NL * ND);

    f32x4 acc = {0.f, 0.f, 0.f, 0.f};
    #pragma unroll 8
    for (int l = l0; l < l1; ++l) {
        float w = wloc[l - l0];                  // LDS broadcast (conflict-free)
        f32x4 v = f4[(size_t)l * (ND / 4) + t];  // coalesced 16B/lane
        acc.x = fmaf(w, v.x, acc.x);
        acc.y = fmaf(w, v.y, acc.y);
        acc.z = fmaf(w, v.z, acc.z);
        acc.w = fmaf(w, v.w, acc.w);
    }

    f32x4* p4 = (f32x4*)(partial + ((size_t)b * CH + c) * ND);
    p4[t] = acc;                                 // deterministic 16B store
}

// Kernel C: out[b,d] = (1/sum_b) * sum_{active c} partial[b][c][d]
// grid = B, block = 256, thread t owns float4 at d = 4t. Writes out fully
// (no memset needed).
__global__ __launch_bounds__(256) void vq_reduce_kernel(
    const float* __restrict__ partial,    // (B, CH, D) ws
    const int* __restrict__ lengths,
    const float* __restrict__ sums,
    float* __restrict__ out)              // (B, D)
{
    const int b = blockIdx.x;
    const int t = threadIdx.x;
    const int len = lengths[b];
    const int ncb = (len + CL - 1) / CL;  // active chunks (>=16, <=32)

    const f32x4* p4 = (const f32x4*)(partial + (size_t)b * CH * ND);

    f32x4 acc = {0.f, 0.f, 0.f, 0.f};
    for (int c = 0; c < ncb; ++c) {
        f32x4 v = p4[(size_t)c * (ND / 4) + t];
        acc.x += v.x; acc.y += v.y; acc.z += v.z; acc.w += v.w;
    }

    const float inv = 1.0f / sums[b];
    f32x4 r = {acc.x * inv, acc.y * inv, acc.z * inv, acc.w * inv};
    ((f32x4*)(out + (size_t)b * ND))[t] = r;
}

extern "C" void kernel_launch(void* const* d_in, const int* in_sizes, int n_in,
                              void* d_out, int out_size, void* d_ws, size_t ws_size,
                              hipStream_t stream) {
    const float* feature = (const float*)d_in[0];   // (B, 2, L, D) f32
    const int*   lengths = (const int*)d_in[1];     // (B,) int
    const int*   vq      = (const int*)d_in[2];     // (B, L, 2) int
    float* out = (float*)d_out;

    float* prob    = (float*)d_ws;                       // B*L floats (256 KiB)
    float* sums    = prob + (size_t)NB * NL;             // B floats
    float* partial = sums + NB;                          // B*CH*D floats (4 MiB), 16B-aligned

    vq_weights_kernel<<<NB, 256, 0, stream>>>(vq, lengths, prob, sums);
    vq_pool_kernel<<<dim3(CH, NB), 256, 0, stream>>>(feature, lengths, prob, partial);
    vq_reduce_kernel<<<NB, 256, 0, stream>>>(partial, lengths, sums, out);
}

// Round 2
// 624.341 us; speedup vs baseline: 1.0051x; 1.0051x over previous
//
#include <hip/hip_runtime.h>

#define NV 320
#define NB 32
#define NL 2048
#define ND 1024
#define CH 64            // l-chunks per batch
#define CL (NL / CH)     // 32 positions per chunk

typedef float f32x4 __attribute__((ext_vector_type(4)));

// Kernel A: per-batch histogram -> per-position prob -> per-batch 1/sum.
// One block per batch, 256 threads. int4 loads = 2 (x,y) pairs per load.
__global__ __launch_bounds__(256) void vq_weights_kernel(
    const int* __restrict__ vq_indices,   // (B, L, 2) int32
    const int* __restrict__ lengths,      // (B,) int32
    float* __restrict__ prob,             // (B, L) ws
    float* __restrict__ inv_sums)         // (B,)  ws  (stores 1/sum)
{
    __shared__ int cx[NV];
    __shared__ int cy[NV];
    __shared__ float wave_sums[4];

    const int b = blockIdx.x;
    const int t = threadIdx.x;

    for (int i = t; i < NV; i += 256) { cx[i] = 0; cy[i] = 0; }
    __syncthreads();

    // histogram over ALL L positions (reference counts unmasked)
    const int4* idx = (const int4*)(vq_indices) + (size_t)b * (NL / 2);
    for (int i = t; i < NL / 2; i += 256) {
        int4 v = idx[i];                  // (x0,y0,x1,y1)
        atomicAdd(&cx[v.x], 1);
        atomicAdd(&cy[v.y], 1);
        atomicAdd(&cx[v.z], 1);
        atomicAdd(&cy[v.w], 1);
    }
    __syncthreads();

    const int len = lengths[b];
    float local = 0.f;
    float2* p2 = (float2*)(prob + (size_t)b * NL);
    for (int i = t; i < NL / 2; i += 256) {
        int4 v = idx[i];
        const int la = 2 * i, lb = 2 * i + 1;
        float pa = (la < len) ? 1.0f / (float)(cx[v.x] + cy[v.y]) : 0.f;
        float pb = (lb < len) ? 1.0f / (float)(cx[v.z] + cy[v.w]) : 0.f;
        p2[i] = make_float2(pa, pb);
        local += pa + pb;
    }
    // wave64 reduce, then cross-wave via LDS
    for (int off = 32; off > 0; off >>= 1)
        local += __shfl_down(local, off, 64);
    if ((t & 63) == 0) wave_sums[t >> 6] = local;
    __syncthreads();
    if (t == 0)
        inv_sums[b] = 1.0f /
            (wave_sums[0] + wave_sums[1] + wave_sums[2] + wave_sums[3]);
}

// Kernel B: partial[b][c][d] = sum_{l in chunk c} prob[b,l] * feat[b,1,l,d]
// grid = (CH, B) = 2048 blocks (32 waves/CU = full occupancy), 256 threads,
// thread t owns float4 at d = 4t. Nontemporal feature loads (read-once).
__global__ __launch_bounds__(256) void vq_pool_kernel(
    const float* __restrict__ feature,    // (B, 2, L, D) f32
    const int* __restrict__ lengths,
    const float* __restrict__ prob,
    float* __restrict__ partial)          // (B, CH, D) ws
{
    const int c = blockIdx.x;
    const int b = blockIdx.y;
    const int len = lengths[b];
    const int l0 = c * CL;
    if (l0 >= len) return;                // fully masked chunk: reducer skips it
    const int n = min(l0 + CL, len) - l0;

    const int t = threadIdx.x;

    __shared__ float wloc[CL];
    if (t < CL) wloc[t] = prob[(size_t)b * NL + l0 + t];
    __syncthreads();

    // feat slice [b, n=1], rows starting at l0
    const f32x4* f4 = (const f32x4*)(feature + ((size_t)b * 2 + 1) * (size_t)NL * ND)
                    + (size_t)l0 * (ND / 4);

    f32x4 acc = {0.f, 0.f, 0.f, 0.f};
    #pragma unroll 8
    for (int l = 0; l < n; ++l) {
        float w = wloc[l];                                        // LDS broadcast
        f32x4 v = __builtin_nontemporal_load(&f4[(size_t)l * (ND / 4) + t]);
        acc += w * v;                                             // packed FMA
    }

    f32x4* p4 = (f32x4*)(partial + ((size_t)b * CH + c) * ND);
    p4[t] = acc;                          // deterministic 16B store (L2-resident for C)
}

// Kernel C: out[b,d] = inv_sum_b * sum_{active c} partial[b][c][d]
// grid = B, block = 256, thread t owns float4 at d = 4t. Writes out fully.
__global__ __launch_bounds__(256) void vq_reduce_kernel(
    const float* __restrict__ partial,    // (B, CH, D) ws
    const int* __restrict__ lengths,
    const float* __restrict__ inv_sums,
    float* __restrict__ out)              // (B, D)
{
    const int b = blockIdx.x;
    const int t = threadIdx.x;
    const int len = lengths[b];
    const int ncb = (len + CL - 1) / CL;  // active chunks (<= CH)

    const f32x4* p4 = (const f32x4*)(partial + (size_t)b * CH * ND);

    f32x4 acc = {0.f, 0.f, 0.f, 0.f};
    for (int cc = 0; cc < ncb; ++cc)
        acc += p4[(size_t)cc * (ND / 4) + t];

    ((f32x4*)(out + (size_t)b * ND))[t] = acc * inv_sums[b];
}

extern "C" void kernel_launch(void* const* d_in, const int* in_sizes, int n_in,
                              void* d_out, int out_size, void* d_ws, size_t ws_size,
                              hipStream_t stream) {
    const float* feature = (const float*)d_in[0];   // (B, 2, L, D) f32
    const int*   lengths = (const int*)d_in[1];     // (B,) int
    const int*   vq      = (const int*)d_in[2];     // (B, L, 2) int
    float* out = (float*)d_out;

    float* prob     = (float*)d_ws;                  // B*L floats (256 KiB)
    float* inv_sums = prob + (size_t)NB * NL;        // B floats
    float* partial  = inv_sums + NB;                 // B*CH*D floats (8 MiB), 16B-aligned

    vq_weights_kernel<<<NB, 256, 0, stream>>>(vq, lengths, prob, inv_sums);
    vq_pool_kernel<<<dim3(CH, NB), 256, 0, stream>>>(feature, lengths, prob, partial);
    vq_reduce_kernel<<<NB, 256, 0, stream>>>(partial, lengths, inv_sums, out);
}